// Round 5
// baseline (686.202 us; speedup 1.0000x reference)
//
#include <hip/hip_runtime.h>

#define DIM 768
#define NEG_SLOPE 0.2f
#define MAXDEG 64   // P(in-degree >= 63) over 10000 Poisson(10) nodes ~ 1e-36

typedef unsigned short ushort_t;
typedef short short8 __attribute__((ext_vector_type(8)));
typedef float floatx4 __attribute__((ext_vector_type(4)));

__device__ __forceinline__ ushort_t f32_to_bf16(float f) {
  unsigned int b = __float_as_uint(f);
  b += 0x7FFFu + ((b >> 16) & 1u);   // RNE
  return (ushort_t)(b >> 16);
}
__device__ __forceinline__ float bf16_to_f32(ushort_t u) {
  return __uint_as_float(((unsigned int)u) << 16);
}
__device__ __forceinline__ float bf16lo(unsigned int u) {
  return __uint_as_float(u << 16);
}
__device__ __forceinline__ float bf16hi(unsigned int u) {
  return __uint_as_float(u & 0xFFFF0000u);
}
__device__ __forceinline__ unsigned int pack_bf16x2(float lo, float hi) {
  return ((unsigned int)f32_to_bf16(lo)) | (((unsigned int)f32_to_bf16(hi)) << 16);
}

// async global->LDS, 16B per lane. LDS dest = wave-uniform base + lane*16.
__device__ __forceinline__ void gl2lds16(const ushort_t* g, ushort_t* l) {
  __builtin_amdgcn_global_load_lds(
      (const __attribute__((address_space(1))) void*)g,
      (__attribute__((address_space(3))) void*)l, 16, 0, 0);
}

// ---- device-wide generation barrier (no cooperative launch needed) --------------
// Safe because ALL blocks are resident by construction: 64 KB static LDS -> 2
// blocks/CU hard cap, __launch_bounds__(256,2) caps VGPR<=256 so registers can't
// lower it, grid 480 <= 512 slots. Agent-scope atomics are device-scope (m20);
// __threadfence() emits the L2-writeback/L1-invalidate for cross-XCD visibility.
__device__ __forceinline__ void grid_barrier(int* cnt, int* gen, int nblk) {
  __syncthreads();
  if (threadIdx.x == 0) {
    __threadfence();                       // release this block's writes
    int g = __hip_atomic_load(gen, __ATOMIC_ACQUIRE, __HIP_MEMORY_SCOPE_AGENT);
    int arrived = __hip_atomic_fetch_add(cnt, 1, __ATOMIC_ACQ_REL,
                                         __HIP_MEMORY_SCOPE_AGENT);
    if (arrived == nblk - 1) {
      __hip_atomic_store(cnt, 0, __ATOMIC_RELAXED, __HIP_MEMORY_SCOPE_AGENT);
      __hip_atomic_store(gen, g + 1, __ATOMIC_RELEASE, __HIP_MEMORY_SCOPE_AGENT);
    } else {
      while (__hip_atomic_load(gen, __ATOMIC_ACQUIRE,
                               __HIP_MEMORY_SCOPE_AGENT) == g) {
        __builtin_amdgcn_s_sleep(8);
      }
    }
    __threadfence();                       // acquire: invalidate stale caches
  }
  __syncthreads();
}

struct MegaArgs {
  const float* x; const int* ei;
  const float* W1; const float* as1; const float* ad1; const float* b1;
  const float* W2; const float* as2; const float* ad2; const float* b2;
  ushort_t* xb; ushort_t* wT1; ushort_t* wT2; ushort_t* Hb;
  int* zbase; int* col;
  float* out;
  int N, E, Etot, MBLK, n4;
};

// -------- bf16 MFMA GEMM phase, 128x128 tile, BK=64, 2-phase dbuf LDS ------------
__device__ __forceinline__ void gemm_phase(
    const ushort_t* __restrict__ A, const ushort_t* __restrict__ Bt,
    const float* __restrict__ att_s, const float* __restrict__ att_d,
    float* __restrict__ a_s, float* __restrict__ a_d,
    ushort_t* __restrict__ Hb, int M, int MBLK,
    ushort_t* AsBase, ushort_t* BsBase) {
  const int K = DIM;
  int ntiles = 8 * MBLK * 6;
  int tid = threadIdx.x;
  int wave = tid >> 6, lane = tid & 63;
  int quad = lane >> 4, l16 = lane & 15;
  int wr = wave >> 1, wc = wave & 1;   // 2x2 wave grid, 64x64 each
  int lr = lane >> 3, lc = lane & 7;

  for (int b = blockIdx.x; b < ntiles; b += gridDim.x) {
    int x = b & 7, sidx = b >> 3;
    int m_local = sidx / 6, nblk = sidx - m_local * 6;
    int mblk = x * MBLK + m_local;
    if (mblk * 128 >= M) continue;     // block-uniform skip
    int m0 = mblk * 128, n0 = nblk * 128;

    floatx4 acc[4][4];
    const floatx4 fzero = {0.f, 0.f, 0.f, 0.f};
#pragma unroll
    for (int i = 0; i < 4; ++i)
#pragma unroll
      for (int j = 0; j < 4; ++j) acc[i][j] = fzero;

    const ushort_t* gA[4];
    const ushort_t* gB[4];
    ushort_t* lA[4];
    ushort_t* lB[4];
#pragma unroll
    for (int t = 0; t < 4; ++t) {
      int r = t * 32 + wave * 8 + lr;               // 0..127
      int g = lc ^ (r & 7);
      gA[t] = A + (size_t)min(m0 + r, M - 1) * K + g * 8;
      gB[t] = Bt + (size_t)(n0 + r) * K + g * 8;
      lA[t] = AsBase + (t * 32 + wave * 8) * 64;
      lB[t] = BsBase + (t * 32 + wave * 8) * 64;
    }

#define GEMM_STAGE(k0_, buf_)                                         \
  {                                                                   \
    _Pragma("unroll")                                                 \
    for (int t = 0; t < 4; ++t) gl2lds16(gA[t] + (k0_), lA[t] + (buf_)*8192); \
    _Pragma("unroll")                                                 \
    for (int t = 0; t < 4; ++t) gl2lds16(gB[t] + (k0_), lB[t] + (buf_)*8192); \
  }

    GEMM_STAGE(0, 0);
    __syncthreads();                   // drains vmcnt(0): buf0 ready
    int cur = 0;

    for (int k0 = 0; k0 < K; k0 += 64) {
      if (k0 + 64 < K) GEMM_STAGE(k0 + 64, cur ^ 1);   // prefetch next tile
      const ushort_t* Ab = AsBase + cur * 8192;
      const ushort_t* Bb = BsBase + cur * 8192;
#pragma unroll
      for (int h = 0; h < 2; ++h) {
        short8 af[4], bfr[4];
#pragma unroll
        for (int i = 0; i < 4; ++i) {
          int ra = wr * 64 + i * 16 + l16;
          af[i] = *(const short8*)(Ab + ra * 64 + ((((h << 2) | quad)) ^ (ra & 7)) * 8);
        }
#pragma unroll
        for (int j = 0; j < 4; ++j) {
          int rb = wc * 64 + j * 16 + l16;
          bfr[j] = *(const short8*)(Bb + rb * 64 + ((((h << 2) | quad)) ^ (rb & 7)) * 8);
        }
#pragma unroll
        for (int i = 0; i < 4; ++i)
#pragma unroll
          for (int j = 0; j < 4; ++j)
            acc[i][j] = __builtin_amdgcn_mfma_f32_16x16x32_bf16(af[i], bfr[j], acc[i][j], 0, 0, 0);
      }
      __syncthreads();                 // drains prefetch; next buf ready
      cur ^= 1;
    }
#undef GEMM_STAGE

    float avs[4], avd[4];
#pragma unroll
    for (int j = 0; j < 4; ++j) {
      int c = n0 + wc * 64 + j * 16 + l16;
      avs[j] = att_s[c];
      avd[j] = att_d[c];
    }

#pragma unroll
    for (int i = 0; i < 4; ++i) {
#pragma unroll
      for (int r2 = 0; r2 < 4; ++r2) {
        int row = m0 + wr * 64 + i * 16 + quad * 4 + r2;
        bool valid = row < M;
        float pvs = 0.f, pvd = 0.f;
#pragma unroll
        for (int j = 0; j < 4; ++j) {
          float v = acc[i][j][r2];
          if (valid) Hb[(size_t)row * DIM + n0 + wc * 64 + j * 16 + l16] = f32_to_bf16(v);
          pvs = fmaf(v, avs[j], pvs);
          pvd = fmaf(v, avd[j], pvd);
        }
#pragma unroll
        for (int off = 1; off < 16; off <<= 1) {
          pvs += __shfl_xor(pvs, off, 64);
          pvd += __shfl_xor(pvd, off, 64);
        }
        if (valid && l16 == 0) {
          atomicAdd(a_s + row, pvs);
          atomicAdd(a_d + row, pvd);
        }
      }
    }
  }
}

// ------- agg phase: single-pass segment softmax + pipelined gather-sum -----------
// Wave per node, grid-stride. Wave-uniform deg/a_d loads go through relaxed
// agent-scope atomic loads (vector path; immune to scalar-cache staleness).
__device__ __forceinline__ void agg_phase(
    const ushort_t* __restrict__ h, const float* __restrict__ a_s,
    float* a_d, int* deg,
    const int* __restrict__ col, const float* __restrict__ bias,
    float* __restrict__ out_f32, ushort_t* __restrict__ out_bf16,
    int relu_mode, int N) {
  int lane = threadIdx.x & 63;
  int wave = threadIdx.x >> 6;
  int c8 = lane * 8, c4 = 512 + lane * 4;
  float4 b0 = *(const float4*)(bias + c8);
  float4 b1v = *(const float4*)(bias + c8 + 4);
  float4 b2v = *(const float4*)(bias + c4);

  for (int node = blockIdx.x * 4 + wave; node < N; node += gridDim.x * 4) {
    int dg = min(__hip_atomic_load(&deg[node], __ATOMIC_RELAXED,
                                   __HIP_MEMORY_SCOPE_AGENT), MAXDEG);
    int base = node * MAXDEG;
    float ad = __hip_atomic_load(&a_d[node], __ATOMIC_RELAXED,
                                 __HIP_MEMORY_SCOPE_AGENT);

    bool has = lane < dg;
    int sc = col[base + min(lane, dg - 1)];
    float v = a_s[sc] + ad;
    v = (v > 0.f) ? v : NEG_SLOPE * v;
    float vmax = v;
#pragma unroll
    for (int off = 32; off > 0; off >>= 1) vmax = fmaxf(vmax, __shfl_xor(vmax, off, 64));
    float ex = has ? __expf(v - vmax) : 0.f;
    float ssum = ex;
#pragma unroll
    for (int off = 32; off > 0; off >>= 1) ssum += __shfl_xor(ssum, off, 64);
    float al = ex * (1.f / ssum);      // 0 for dead lanes

    float acc8[8];
    float acc4[4];
#pragma unroll
    for (int k = 0; k < 8; ++k) acc8[k] = 0.f;
#pragma unroll
    for (int k = 0; k < 4; ++k) acc4[k] = 0.f;

    uint4 uA[4], uB[4];
    ushort4 tA[4], tB[4];
    float wA[4], wB[4];

#define GAT_LOADC(b_, u_, t_, w_)                                     \
  {                                                                   \
    _Pragma("unroll")                                                 \
    for (int q = 0; q < 4; ++q) {                                     \
      int j_ = (b_) + q;                                              \
      w_[q] = __shfl(al, j_, 64);                                     \
      int s_ = __shfl(sc, j_, 64);                                    \
      const ushort_t* hr_ = h + (size_t)s_ * DIM;                     \
      u_[q] = *(const uint4*)(hr_ + lane * 8);                        \
      t_[q] = *(const ushort4*)(hr_ + 512 + lane * 4);                \
    }                                                                 \
  }

#define GAT_FMAC(u_, t_, w_)                                          \
  {                                                                   \
    _Pragma("unroll")                                                 \
    for (int q = 0; q < 4; ++q) {                                     \
      float w = w_[q];                                                \
      acc8[0] = fmaf(w, bf16lo(u_[q].x), acc8[0]);                    \
      acc8[1] = fmaf(w, bf16hi(u_[q].x), acc8[1]);                    \
      acc8[2] = fmaf(w, bf16lo(u_[q].y), acc8[2]);                    \
      acc8[3] = fmaf(w, bf16hi(u_[q].y), acc8[3]);                    \
      acc8[4] = fmaf(w, bf16lo(u_[q].z), acc8[4]);                    \
      acc8[5] = fmaf(w, bf16hi(u_[q].z), acc8[5]);                    \
      acc8[6] = fmaf(w, bf16lo(u_[q].w), acc8[6]);                    \
      acc8[7] = fmaf(w, bf16hi(u_[q].w), acc8[7]);                    \
      acc4[0] = fmaf(w, bf16_to_f32(t_[q].x), acc4[0]);               \
      acc4[1] = fmaf(w, bf16_to_f32(t_[q].y), acc4[1]);               \
      acc4[2] = fmaf(w, bf16_to_f32(t_[q].z), acc4[2]);               \
      acc4[3] = fmaf(w, bf16_to_f32(t_[q].w), acc4[3]);               \
    }                                                                 \
  }

    int dgc = (dg + 3) & ~3;           // chunk-of-4 round-up (w=0 dup-row tail)
    GAT_LOADC(0, uA, tA, wA);
    for (int bb = 0; bb < dgc; bb += 8) {
      if (bb + 4 < dgc) GAT_LOADC(bb + 4, uB, tB, wB);
      GAT_FMAC(uA, tA, wA);
      if (bb + 8 < dgc) GAT_LOADC(bb + 8, uA, tA, wA);
      if (bb + 4 < dgc) GAT_FMAC(uB, tB, wB);
    }
#undef GAT_LOADC
#undef GAT_FMAC

    size_t ob = (size_t)node * DIM;
    float o[12];
    o[0] = acc8[0] + b0.x; o[1] = acc8[1] + b0.y;
    o[2] = acc8[2] + b0.z; o[3] = acc8[3] + b0.w;
    o[4] = acc8[4] + b1v.x; o[5] = acc8[5] + b1v.y;
    o[6] = acc8[6] + b1v.z; o[7] = acc8[7] + b1v.w;
    o[8] = acc4[0] + b2v.x; o[9] = acc4[1] + b2v.y;
    o[10] = acc4[2] + b2v.z; o[11] = acc4[3] + b2v.w;
    if (relu_mode) {
#pragma unroll
      for (int k = 0; k < 12; ++k) o[k] = fmaxf(o[k], 0.f);
      uint4 s0;
      s0.x = pack_bf16x2(o[0], o[1]);
      s0.y = pack_bf16x2(o[2], o[3]);
      s0.z = pack_bf16x2(o[4], o[5]);
      s0.w = pack_bf16x2(o[6], o[7]);
      *(uint4*)(out_bf16 + ob + c8) = s0;
      uint2 s1;
      s1.x = pack_bf16x2(o[8], o[9]);
      s1.y = pack_bf16x2(o[10], o[11]);
      *(uint2*)(out_bf16 + ob + c4) = s1;
    } else {
      *(float4*)(out_f32 + ob + c8) = make_float4(o[0], o[1], o[2], o[3]);
      *(float4*)(out_f32 + ob + c8 + 4) = make_float4(o[4], o[5], o[6], o[7]);
      *(float4*)(out_f32 + ob + c4) = make_float4(o[8], o[9], o[10], o[11]);
    }
  }
}

// ------------------- mega-kernel: 6 phases, 5 spin barriers ----------------------
__global__ __launch_bounds__(256, 2)
void mega_kernel(MegaArgs a) {
  __shared__ __align__(16) ushort_t As[2][128 * 64];   // 32 KB
  __shared__ __align__(16) ushort_t Bs[2][128 * 64];   // 32 KB

  int* deg    = a.zbase;
  float* a_s1 = (float*)(a.zbase + a.N);
  float* a_d1 = (float*)(a.zbase + 2 * a.N);
  float* a_s2 = (float*)(a.zbase + 3 * a.N);
  float* a_d2 = (float*)(a.zbase + 4 * a.N);
  int* bcnt   = a.zbase + 5 * a.N;     // barrier state (memset to 0 pre-launch)
  int* bgen   = a.zbase + 5 * a.N + 1;
  int nblk    = gridDim.x;

  // ---- P0: prep (W transpose via LDS overlay, x->bf16); zbase zeroed by memset --
  {
    ushort_t (*tile)[65] = reinterpret_cast<ushort_t(*)[65]>(&As[0][0]);
    int t = threadIdx.x;
    for (int b = blockIdx.x; b < 288; b += gridDim.x) {
      int mat = b / 144;
      int ti = b - mat * 144;
      int tr = (ti / 12) * 64;   // k-base (row of W)
      int tc = (ti % 12) * 64;   // n-base (col of W)
      const float* W = mat ? a.W2 : a.W1;
      ushort_t* wT = mat ? a.wT2 : a.wT1;
      int lr = t >> 4, lc4 = (t & 15) * 4;
#pragma unroll
      for (int p = 0; p < 4; ++p) {
        int row = lr + p * 16;
        float4 v = *(const float4*)(W + (size_t)(tr + row) * DIM + tc + lc4);
        tile[row][lc4 + 0] = f32_to_bf16(v.x);
        tile[row][lc4 + 1] = f32_to_bf16(v.y);
        tile[row][lc4 + 2] = f32_to_bf16(v.z);
        tile[row][lc4 + 3] = f32_to_bf16(v.w);
      }
      __syncthreads();
      int n = t & 63, kb = (t >> 6) * 16;
      ushort_t tmp[16];
#pragma unroll
      for (int i = 0; i < 16; ++i) tmp[i] = tile[kb + i][n];
      ushort_t* dst = wT + (size_t)(tc + n) * DIM + tr + kb;
      *(uint4*)(dst) = *(const uint4*)(&tmp[0]);
      *(uint4*)(dst + 8) = *(const uint4*)(&tmp[8]);
      __syncthreads();                 // tile reused next iteration
    }
    for (int i = blockIdx.x * 256 + threadIdx.x; i < a.n4; i += gridDim.x * 256) {
      float4 v = ((const float4*)a.x)[i];
      ushort4 o;
      o.x = f32_to_bf16(v.x); o.y = f32_to_bf16(v.y);
      o.z = f32_to_bf16(v.z); o.w = f32_to_bf16(v.w);
      ((ushort4*)a.xb)[i] = o;
    }
  }
  grid_barrier(bcnt, bgen, nblk);

  // ---- P1: CSR-lite slot fill ----
  for (int e = blockIdx.x * 256 + threadIdx.x; e < a.Etot; e += gridDim.x * 256) {
    int s, d;
    if (e < a.E) { s = a.ei[e]; d = a.ei[a.E + e]; }
    else         { s = e - a.E; d = e - a.E; }
    int slot = atomicAdd(&deg[d], 1);
    if (slot < MAXDEG) a.col[(size_t)d * MAXDEG + slot] = s;
  }
  grid_barrier(bcnt, bgen, nblk);

  // ---- P2: gemm layer 1 ----
  gemm_phase(a.xb, a.wT1, a.as1, a.ad1, a_s1, a_d1, a.Hb, a.N, a.MBLK,
             &As[0][0], &Bs[0][0]);
  grid_barrier(bcnt, bgen, nblk);

  // ---- P3: agg layer 1 -> xb (relu, bf16) ----
  agg_phase(a.Hb, a_s1, a_d1, deg, a.col, a.b1, nullptr, a.xb, 1, a.N);
  grid_barrier(bcnt, bgen, nblk);

  // ---- P4: gemm layer 2 ----
  gemm_phase(a.xb, a.wT2, a.as2, a.ad2, a_s2, a_d2, a.Hb, a.N, a.MBLK,
             &As[0][0], &Bs[0][0]);
  grid_barrier(bcnt, bgen, nblk);

  // ---- P5: agg layer 2 -> out (f32) ----
  agg_phase(a.Hb, a_s2, a_d2, deg, a.col, a.b2, a.out, nullptr, 0, a.N);
}

extern "C" void kernel_launch(void* const* d_in, const int* in_sizes, int n_in,
                              void* d_out, int out_size, void* d_ws, size_t ws_size,
                              hipStream_t stream) {
  const float* x   = (const float*)d_in[0];
  const int*   ei  = (const int*)d_in[1];
  const float* W1  = (const float*)d_in[2];
  const float* as1 = (const float*)d_in[3];
  const float* ad1 = (const float*)d_in[4];
  const float* b1  = (const float*)d_in[5];
  const float* W2  = (const float*)d_in[6];
  const float* as2 = (const float*)d_in[7];
  const float* ad2 = (const float*)d_in[8];
  const float* b2  = (const float*)d_in[9];

  const int N = in_sizes[0] / DIM;   // 10000
  const int E = in_sizes[1] / 2;     // 100000
  const int Etot = E + N;

  char* p = (char*)d_ws;
  auto alloc = [&](size_t bytes) {
    char* q = p;
    p += (bytes + 255) & ~(size_t)255;
    return q;
  };
  ushort_t* Hb     = (ushort_t*)alloc((size_t)N * DIM * 2);
  ushort_t* xb     = (ushort_t*)alloc((size_t)N * DIM * 2);
  ushort_t* wT1    = (ushort_t*)alloc((size_t)DIM * DIM * 2);
  ushort_t* wT2    = (ushort_t*)alloc((size_t)DIM * DIM * 2);
  // zeroed region: deg | a_s1 | a_d1 | a_s2 | a_d2 | barrier cnt,gen
  int*      zbase  = (int*)alloc((size_t)5 * N * 4 + 16);
  int*      col    = (int*)alloc((size_t)N * MAXDEG * 4);

  int MB = (N + 127) / 128;          // 79 m-blocks
  int MBLK = (MB + 7) / 8;           // 10 m-blocks per XCD strip
  int G = 8 * MBLK * 6;              // 480 blocks; 64KB LDS -> 2/CU -> all resident

  MegaArgs a;
  a.x = x; a.ei = ei;
  a.W1 = W1; a.as1 = as1; a.ad1 = ad1; a.b1 = b1;
  a.W2 = W2; a.as2 = as2; a.ad2 = ad2; a.b2 = b2;
  a.xb = xb; a.wT1 = wT1; a.wT2 = wT2; a.Hb = Hb;
  a.zbase = zbase; a.col = col;
  a.out = (float*)d_out;
  a.N = N; a.E = E; a.Etot = Etot; a.MBLK = MBLK;
  a.n4 = N * DIM / 4;

  // zero deg/a_s/a_d + barrier state (self-resetting across graph replays)
  hipMemsetAsync(zbase, 0, (size_t)5 * N * 4 + 16, stream);
  mega_kernel<<<G, 256, 0, stream>>>(a);
}

// Round 8
// 196.007 us; speedup vs baseline: 3.5009x; 3.5009x over previous
//
#include <hip/hip_runtime.h>

#define DIM 768
#define NEG_SLOPE 0.2f
#define MAXDEG 64   // P(in-degree >= 63) over 10000 Poisson(10) nodes ~ 1e-36

typedef unsigned short ushort_t;
typedef short short8 __attribute__((ext_vector_type(8)));
typedef float floatx4 __attribute__((ext_vector_type(4)));

__device__ __forceinline__ ushort_t f32_to_bf16(float f) {
  unsigned int b = __float_as_uint(f);
  b += 0x7FFFu + ((b >> 16) & 1u);   // RNE
  return (ushort_t)(b >> 16);
}
__device__ __forceinline__ float bf16_to_f32(ushort_t u) {
  return __uint_as_float(((unsigned int)u) << 16);
}
__device__ __forceinline__ float bf16lo(unsigned int u) {
  return __uint_as_float(u << 16);
}
__device__ __forceinline__ float bf16hi(unsigned int u) {
  return __uint_as_float(u & 0xFFFF0000u);
}
__device__ __forceinline__ unsigned int pack_bf16x2(float lo, float hi) {
  return ((unsigned int)f32_to_bf16(lo)) | (((unsigned int)f32_to_bf16(hi)) << 16);
}

// async global->LDS, 16B per lane. LDS dest = wave-uniform base + lane*16.
__device__ __forceinline__ void gl2lds16(const ushort_t* g, ushort_t* l) {
  __builtin_amdgcn_global_load_lds(
      (const __attribute__((address_space(1))) void*)g,
      (__attribute__((address_space(3))) void*)l, 16, 0, 0);
}

// ------- fused prep: W transposes (LDS-tiled, coalesced) + x->bf16 + zero ---------
__global__ __launch_bounds__(256)
void prep_kernel(const float* __restrict__ x, ushort_t* __restrict__ xb, int n4,
                 const float* __restrict__ W1, ushort_t* __restrict__ wT1,
                 const float* __restrict__ W2, ushort_t* __restrict__ wT2,
                 int* __restrict__ zbase, int nz4) {
  __shared__ ushort_t tile[64][65];
  int b = blockIdx.x;
  int t = threadIdx.x;
  if (b < 288) {
    int mat = b / 144;
    int ti = b - mat * 144;
    int tr = (ti / 12) * 64;   // k-base (row of W)
    int tc = (ti % 12) * 64;   // n-base (col of W)
    const float* W = mat ? W2 : W1;
    ushort_t* wT = mat ? wT2 : wT1;
    int lr = t >> 4, lc4 = (t & 15) * 4;
#pragma unroll
    for (int p = 0; p < 4; ++p) {
      int row = lr + p * 16;
      float4 v = *(const float4*)(W + (size_t)(tr + row) * DIM + tc + lc4);
      tile[row][lc4 + 0] = f32_to_bf16(v.x);
      tile[row][lc4 + 1] = f32_to_bf16(v.y);
      tile[row][lc4 + 2] = f32_to_bf16(v.z);
      tile[row][lc4 + 3] = f32_to_bf16(v.w);
    }
    __syncthreads();
    int n = t & 63, kb = (t >> 6) * 16;
    ushort_t tmp[16];
#pragma unroll
    for (int i = 0; i < 16; ++i) tmp[i] = tile[kb + i][n];
    ushort_t* dst = wT + (size_t)(tc + n) * DIM + tr + kb;
    *(uint4*)(dst) = *(const uint4*)(&tmp[0]);
    *(uint4*)(dst + 8) = *(const uint4*)(&tmp[8]);
  } else {
    int i = (b - 288) * 256 + t;
    if (i < n4) {
      float4 v = ((const float4*)x)[i];
      ushort4 o;
      o.x = f32_to_bf16(v.x); o.y = f32_to_bf16(v.y);
      o.z = f32_to_bf16(v.z); o.w = f32_to_bf16(v.w);
      ((ushort4*)xb)[i] = o;
    }
    if (i < nz4) {
      ((uint4*)zbase)[i] = make_uint4(0, 0, 0, 0);
    }
  }
}

// -------- bf16 MFMA GEMM, 128x128 tile, BK=64, 2-phase double-buffered LDS --------
// Blocks >= gemmBlocks run the (independent) CSR-lite slot-fill: both depend only
// on prep, so they share one dispatch (layer-1 launch only). Grid 8*MBLK*6 for the
// gemm part: XCD x = blockIdx&7 owns a contiguous m-strip; B (1.2 MB) L2-resident.
__global__ __launch_bounds__(256)
void gemm_kernel(const ushort_t* __restrict__ A, const ushort_t* __restrict__ Bt,
                 const float* __restrict__ att_s, const float* __restrict__ att_d,
                 float* __restrict__ a_s, float* __restrict__ a_d,
                 ushort_t* __restrict__ Hb, int M, int MBLK,
                 const int* __restrict__ ei, int* __restrict__ degw,
                 int* __restrict__ colw, int E, int Etot, int gemmBlocks) {
  const int K = DIM;
  __shared__ __align__(16) ushort_t As[2][128 * 64];   // 32 KB
  __shared__ __align__(16) ushort_t Bs[2][128 * 64];   // 32 KB
  int b = blockIdx.x;
  if (b >= gemmBlocks) {               // fused CSR path (layer-1 launch only)
    int e = (b - gemmBlocks) * 256 + threadIdx.x;
    if (e < Etot) {
      int s, d;
      if (e < E) { s = ei[e]; d = ei[E + e]; }
      else       { s = e - E; d = e - E; }
      int slot = atomicAdd(&degw[d], 1);
      if (slot < MAXDEG) colw[(size_t)d * MAXDEG + slot] = s;
    }
    return;
  }
  int x = b & 7, sidx = b >> 3;
  int m_local = sidx / 6, nblk = sidx - m_local * 6;
  int mblk = x * MBLK + m_local;
  if (mblk * 128 >= M) return;         // uniform per block: safe early-out
  int m0 = mblk * 128, n0 = nblk * 128;
  int tid = threadIdx.x;
  int wave = tid >> 6, lane = tid & 63;
  int quad = lane >> 4, l16 = lane & 15;
  int wr = wave >> 1, wc = wave & 1;   // 2x2 wave grid, 64x64 each

  floatx4 acc[4][4];
  const floatx4 fzero = {0.f, 0.f, 0.f, 0.f};
#pragma unroll
  for (int i = 0; i < 4; ++i)
#pragma unroll
    for (int j = 0; j < 4; ++j) acc[i][j] = fzero;

  int lr = lane >> 3, lc = lane & 7;
  const ushort_t* gA[4];
  const ushort_t* gB[4];
  ushort_t* lA[4];
  ushort_t* lB[4];
#pragma unroll
  for (int t = 0; t < 4; ++t) {
    int r = t * 32 + wave * 8 + lr;                 // 0..127
    int g = lc ^ (r & 7);
    gA[t] = A + (size_t)min(m0 + r, M - 1) * K + g * 8;
    gB[t] = Bt + (size_t)(n0 + r) * K + g * 8;
    lA[t] = &As[0][(t * 32 + wave * 8) * 64];
    lB[t] = &Bs[0][(t * 32 + wave * 8) * 64];
  }

#define GEMM_STAGE(k0_, buf_)                                         \
  {                                                                   \
    _Pragma("unroll")                                                 \
    for (int t = 0; t < 4; ++t) gl2lds16(gA[t] + (k0_), lA[t] + (buf_)*8192); \
    _Pragma("unroll")                                                 \
    for (int t = 0; t < 4; ++t) gl2lds16(gB[t] + (k0_), lB[t] + (buf_)*8192); \
  }

  GEMM_STAGE(0, 0);
  __syncthreads();                     // drains vmcnt(0): buf0 ready
  int cur = 0;

  for (int k0 = 0; k0 < K; k0 += 64) {
    if (k0 + 64 < K) GEMM_STAGE(k0 + 64, cur ^ 1);   // prefetch next tile
    const ushort_t* Ab = &As[cur][0];
    const ushort_t* Bb = &Bs[cur][0];
#pragma unroll
    for (int h = 0; h < 2; ++h) {
      short8 af[4], bfr[4];
#pragma unroll
      for (int i = 0; i < 4; ++i) {
        int ra = wr * 64 + i * 16 + l16;
        af[i] = *(const short8*)(Ab + ra * 64 + ((((h << 2) | quad)) ^ (ra & 7)) * 8);
      }
#pragma unroll
      for (int j = 0; j < 4; ++j) {
        int rb = wc * 64 + j * 16 + l16;
        bfr[j] = *(const short8*)(Bb + rb * 64 + ((((h << 2) | quad)) ^ (rb & 7)) * 8);
      }
#pragma unroll
      for (int i = 0; i < 4; ++i)
#pragma unroll
        for (int j = 0; j < 4; ++j)
          acc[i][j] = __builtin_amdgcn_mfma_f32_16x16x32_bf16(af[i], bfr[j], acc[i][j], 0, 0, 0);
    }
    __syncthreads();                   // drains prefetch; next buf ready
    cur ^= 1;
  }

  float avs[4], avd[4];
#pragma unroll
  for (int j = 0; j < 4; ++j) {
    int c = n0 + wc * 64 + j * 16 + l16;
    avs[j] = att_s[c];
    avd[j] = att_d[c];
  }

#pragma unroll
  for (int i = 0; i < 4; ++i) {
#pragma unroll
    for (int r2 = 0; r2 < 4; ++r2) {
      int row = m0 + wr * 64 + i * 16 + quad * 4 + r2;
      bool valid = row < M;
      float pvs = 0.f, pvd = 0.f;
#pragma unroll
      for (int j = 0; j < 4; ++j) {
        float v = acc[i][j][r2];
        if (valid) Hb[(size_t)row * DIM + n0 + wc * 64 + j * 16 + l16] = f32_to_bf16(v);
        pvs = fmaf(v, avs[j], pvs);
        pvd = fmaf(v, avd[j], pvd);
      }
#pragma unroll
      for (int off = 1; off < 16; off <<= 1) {
        pvs += __shfl_xor(pvs, off, 64);
        pvd += __shfl_xor(pvd, off, 64);
      }
      if (valid && l16 == 0) {
        atomicAdd(a_s + row, pvs);
        atomicAdd(a_d + row, pvd);
      }
    }
  }
}

// ---------------- wave-per-node segment softmax + gather-sum (bf16 h) ----------------
// Chunk-0 h-row loads are issued BEFORE the softmax latency chain (they depend
// only on col, not alpha); weights are shuffled in after softmax completes. Dead
// lanes duplicate a valid src (cached row, weight 0) so no per-slot guards.
__global__ __launch_bounds__(256)
void aggregate_kernel(const ushort_t* __restrict__ h, const float* __restrict__ a_s,
                      const float* __restrict__ a_d, const int* __restrict__ deg,
                      const int* __restrict__ col, const float* __restrict__ bias,
                      float* __restrict__ out_f32, ushort_t* __restrict__ out_bf16,
                      int relu_mode, int N) {
  int wave = threadIdx.x >> 6, lane = threadIdx.x & 63;
  int node = blockIdx.x * 4 + wave;
  if (node >= N) return;
  int dg = min(deg[node], MAXDEG);     // >=1 always (self-loop)
  int base = node * MAXDEG;
  float ad = a_d[node];

  bool has = lane < dg;
  int sc = col[base + min(lane, dg - 1)];   // dead lanes dup last valid edge

  uint4 uA[4], uB[4];
  ushort4 tA[4], tB[4];
  float wA[4], wB[4];

#define GAT_LOADR(b_, u_, t_)                                         \
  {                                                                   \
    _Pragma("unroll")                                                 \
    for (int q = 0; q < 4; ++q) {                                     \
      int s_ = __shfl(sc, (b_) + q, 64);                              \
      const ushort_t* hr_ = h + (size_t)s_ * DIM;                     \
      u_[q] = *(const uint4*)(hr_ + lane * 8);                        \
      t_[q] = *(const ushort4*)(hr_ + 512 + lane * 4);                \
    }                                                                 \
  }

#define GAT_LOADW(b_, w_)                                             \
  {                                                                   \
    _Pragma("unroll")                                                 \
    for (int q = 0; q < 4; ++q) w_[q] = __shfl(al, (b_) + q, 64);     \
  }

#define GAT_FMAC(u_, t_, w_)                                          \
  {                                                                   \
    _Pragma("unroll")                                                 \
    for (int q = 0; q < 4; ++q) {                                     \
      float w = w_[q];                                                \
      acc8[0] = fmaf(w, bf16lo(u_[q].x), acc8[0]);                    \
      acc8[1] = fmaf(w, bf16hi(u_[q].x), acc8[1]);                    \
      acc8[2] = fmaf(w, bf16lo(u_[q].y), acc8[2]);                    \
      acc8[3] = fmaf(w, bf16hi(u_[q].y), acc8[3]);                    \
      acc8[4] = fmaf(w, bf16lo(u_[q].z), acc8[4]);                    \
      acc8[5] = fmaf(w, bf16hi(u_[q].z), acc8[5]);                    \
      acc8[6] = fmaf(w, bf16lo(u_[q].w), acc8[6]);                    \
      acc8[7] = fmaf(w, bf16hi(u_[q].w), acc8[7]);                    \
      acc4[0] = fmaf(w, bf16_to_f32(t_[q].x), acc4[0]);               \
      acc4[1] = fmaf(w, bf16_to_f32(t_[q].y), acc4[1]);               \
      acc4[2] = fmaf(w, bf16_to_f32(t_[q].z), acc4[2]);               \
      acc4[3] = fmaf(w, bf16_to_f32(t_[q].w), acc4[3]);               \
    }                                                                 \
  }

  // chunk-0 rows in flight while the softmax chain (random a_s gather + 12
  // shuffles + exp) runs
  GAT_LOADR(0, uA, tA);

  float v = a_s[sc] + ad;
  v = (v > 0.f) ? v : NEG_SLOPE * v;
  float vmax = v;
#pragma unroll
  for (int off = 32; off > 0; off >>= 1) vmax = fmaxf(vmax, __shfl_xor(vmax, off, 64));
  float ex = has ? __expf(v - vmax) : 0.f;
  float ssum = ex;
#pragma unroll
  for (int off = 32; off > 0; off >>= 1) ssum += __shfl_xor(ssum, off, 64);
  float al = ex * (1.f / ssum);        // per-lane alpha; 0 for dead lanes

  float acc8[8];
  float acc4[4];
#pragma unroll
  for (int k = 0; k < 8; ++k) acc8[k] = 0.f;
#pragma unroll
  for (int k = 0; k < 4; ++k) acc4[k] = 0.f;

  GAT_LOADW(0, wA);
  int dgc = (dg + 3) & ~3;             // chunk-of-4 round-up (w=0 dup-row tail)
  for (int bb = 0; bb < dgc; bb += 8) {
    if (bb + 4 < dgc) { GAT_LOADR(bb + 4, uB, tB); GAT_LOADW(bb + 4, wB); }
    GAT_FMAC(uA, tA, wA);
    if (bb + 8 < dgc) { GAT_LOADR(bb + 8, uA, tA); GAT_LOADW(bb + 8, wA); }
    if (bb + 4 < dgc) GAT_FMAC(uB, tB, wB);
  }
#undef GAT_LOADR
#undef GAT_LOADW
#undef GAT_FMAC

  size_t ob = (size_t)node * DIM;
  int c8 = lane * 8, c4 = 512 + lane * 4;
  float4 b0 = *(const float4*)(bias + c8);
  float4 b1 = *(const float4*)(bias + c8 + 4);
  float4 b2 = *(const float4*)(bias + c4);
  float o[12];
  o[0] = acc8[0] + b0.x; o[1] = acc8[1] + b0.y;
  o[2] = acc8[2] + b0.z; o[3] = acc8[3] + b0.w;
  o[4] = acc8[4] + b1.x; o[5] = acc8[5] + b1.y;
  o[6] = acc8[6] + b1.z; o[7] = acc8[7] + b1.w;
  o[8] = acc4[0] + b2.x; o[9] = acc4[1] + b2.y;
  o[10] = acc4[2] + b2.z; o[11] = acc4[3] + b2.w;
  if (relu_mode) {
#pragma unroll
    for (int k = 0; k < 12; ++k) o[k] = fmaxf(o[k], 0.f);
    uint4 s0;
    s0.x = pack_bf16x2(o[0], o[1]);
    s0.y = pack_bf16x2(o[2], o[3]);
    s0.z = pack_bf16x2(o[4], o[5]);
    s0.w = pack_bf16x2(o[6], o[7]);
    *(uint4*)(out_bf16 + ob + c8) = s0;
    uint2 s1;
    s1.x = pack_bf16x2(o[8], o[9]);
    s1.y = pack_bf16x2(o[10], o[11]);
    *(uint2*)(out_bf16 + ob + c4) = s1;
  } else {
    *(float4*)(out_f32 + ob + c8) = make_float4(o[0], o[1], o[2], o[3]);
    *(float4*)(out_f32 + ob + c8 + 4) = make_float4(o[4], o[5], o[6], o[7]);
    *(float4*)(out_f32 + ob + c4) = make_float4(o[8], o[9], o[10], o[11]);
  }
}

extern "C" void kernel_launch(void* const* d_in, const int* in_sizes, int n_in,
                              void* d_out, int out_size, void* d_ws, size_t ws_size,
                              hipStream_t stream) {
  const float* x   = (const float*)d_in[0];
  const int*   ei  = (const int*)d_in[1];
  const float* W1  = (const float*)d_in[2];
  const float* as1 = (const float*)d_in[3];
  const float* ad1 = (const float*)d_in[4];
  const float* b1  = (const float*)d_in[5];
  const float* W2  = (const float*)d_in[6];
  const float* as2 = (const float*)d_in[7];
  const float* ad2 = (const float*)d_in[8];
  const float* b2  = (const float*)d_in[9];

  const int N = in_sizes[0] / DIM;   // 10000
  const int E = in_sizes[1] / 2;     // 100000
  const int Etot = E + N;

  char* p = (char*)d_ws;
  auto alloc = [&](size_t bytes) {
    char* q = p;
    p += (bytes + 255) & ~(size_t)255;
    return q;
  };
  ushort_t* Hb     = (ushort_t*)alloc((size_t)N * DIM * 2);
  ushort_t* xb     = (ushort_t*)alloc((size_t)N * DIM * 2);
  ushort_t* wT1    = (ushort_t*)alloc((size_t)DIM * DIM * 2);
  ushort_t* wT2    = (ushort_t*)alloc((size_t)DIM * DIM * 2);
  // contiguous zeroed region: deg | a_s1 | a_d1 | a_s2 | a_d2  (zeroed in prep)
  int*      zbase  = (int*)alloc((size_t)5 * N * 4 + 16);
  int*      deg    = zbase;
  float*    a_s1   = (float*)(zbase + N);
  float*    a_d1   = (float*)(zbase + 2 * N);
  float*    a_s2   = (float*)(zbase + 3 * N);
  float*    a_d2   = (float*)(zbase + 4 * N);
  int*      col    = (int*)alloc((size_t)N * MAXDEG * 4);

  int n4 = N * DIM / 4;
  int nz4 = (5 * N + 3) / 4;
  int prep_blocks = 288 + (n4 + 255) / 256;
  prep_kernel<<<prep_blocks, 256, 0, stream>>>(x, xb, n4, W1, wT1, W2, wT2,
                                               zbase, nz4);

  int MB = (N + 127) / 128;          // 79 m-blocks
  int MBLK = (MB + 7) / 8;           // 10 m-blocks per XCD strip
  int gemm_blocks = 8 * MBLK * 6;    // 480
  int csr_blocks = (Etot + 255) / 256;           // 430
  int agg_blocks = (N + 3) / 4;      // 2500

  // Layer 1 (gemm + fused CSR slot-fill: both depend only on prep)
  gemm_kernel<<<gemm_blocks + csr_blocks, 256, 0, stream>>>(
      xb, wT1, as1, ad1, a_s1, a_d1, Hb, N, MBLK, ei, deg, col, E, Etot, gemm_blocks);
  aggregate_kernel<<<agg_blocks, 256, 0, stream>>>(Hb, a_s1, a_d1, deg, col, b1,
                                                   nullptr, xb, 1, N);
  // Layer 2
  gemm_kernel<<<gemm_blocks, 256, 0, stream>>>(
      xb, wT2, as2, ad2, a_s2, a_d2, Hb, N, MBLK, ei, deg, col, E, 0, gemm_blocks);
  aggregate_kernel<<<agg_blocks, 256, 0, stream>>>(Hb, a_s2, a_d2, deg, col, b2,
                                                   (float*)d_out, nullptr, 0, N);
}

// Round 9
// 195.975 us; speedup vs baseline: 3.5015x; 1.0002x over previous
//
#include <hip/hip_runtime.h>

#define DIM 768
#define NEG_SLOPE 0.2f
#define MAXDEG 64   // P(in-degree >= 63) over 10000 Poisson(10) nodes ~ 1e-36

typedef unsigned short ushort_t;
typedef short short8 __attribute__((ext_vector_type(8)));
typedef float floatx4 __attribute__((ext_vector_type(4)));

__device__ __forceinline__ ushort_t f32_to_bf16(float f) {
  unsigned int b = __float_as_uint(f);
  b += 0x7FFFu + ((b >> 16) & 1u);   // RNE
  return (ushort_t)(b >> 16);
}
__device__ __forceinline__ float bf16_to_f32(ushort_t u) {
  return __uint_as_float(((unsigned int)u) << 16);
}
__device__ __forceinline__ float bf16lo(unsigned int u) {
  return __uint_as_float(u << 16);
}
__device__ __forceinline__ float bf16hi(unsigned int u) {
  return __uint_as_float(u & 0xFFFF0000u);
}
__device__ __forceinline__ unsigned int pack_bf16x2(float lo, float hi) {
  return ((unsigned int)f32_to_bf16(lo)) | (((unsigned int)f32_to_bf16(hi)) << 16);
}

// async global->LDS, 16B per lane. LDS dest = wave-uniform base + lane*16.
__device__ __forceinline__ void gl2lds16(const ushort_t* g, ushort_t* l) {
  __builtin_amdgcn_global_load_lds(
      (const __attribute__((address_space(1))) void*)g,
      (__attribute__((address_space(3))) void*)l, 16, 0, 0);
}

// ------- fused prep: W transposes (LDS-tiled, coalesced) + x->bf16 + zero ---------
__global__ __launch_bounds__(256)
void prep_kernel(const float* __restrict__ x, ushort_t* __restrict__ xb, int n4,
                 const float* __restrict__ W1, ushort_t* __restrict__ wT1,
                 const float* __restrict__ W2, ushort_t* __restrict__ wT2,
                 int* __restrict__ zbase, int nz4) {
  __shared__ ushort_t tile[64][65];
  int b = blockIdx.x;
  int t = threadIdx.x;
  if (b < 288) {
    int mat = b / 144;
    int ti = b - mat * 144;
    int tr = (ti / 12) * 64;   // k-base (row of W)
    int tc = (ti % 12) * 64;   // n-base (col of W)
    const float* W = mat ? W2 : W1;
    ushort_t* wT = mat ? wT2 : wT1;
    int lr = t >> 4, lc4 = (t & 15) * 4;
#pragma unroll
    for (int p = 0; p < 4; ++p) {
      int row = lr + p * 16;
      float4 v = *(const float4*)(W + (size_t)(tr + row) * DIM + tc + lc4);
      tile[row][lc4 + 0] = f32_to_bf16(v.x);
      tile[row][lc4 + 1] = f32_to_bf16(v.y);
      tile[row][lc4 + 2] = f32_to_bf16(v.z);
      tile[row][lc4 + 3] = f32_to_bf16(v.w);
    }
    __syncthreads();
    int n = t & 63, kb = (t >> 6) * 16;
    ushort_t tmp[16];
#pragma unroll
    for (int i = 0; i < 16; ++i) tmp[i] = tile[kb + i][n];
    ushort_t* dst = wT + (size_t)(tc + n) * DIM + tr + kb;
    *(uint4*)(dst) = *(const uint4*)(&tmp[0]);
    *(uint4*)(dst + 8) = *(const uint4*)(&tmp[8]);
  } else {
    int i = (b - 288) * 256 + t;
    if (i < n4) {
      float4 v = ((const float4*)x)[i];
      ushort4 o;
      o.x = f32_to_bf16(v.x); o.y = f32_to_bf16(v.y);
      o.z = f32_to_bf16(v.z); o.w = f32_to_bf16(v.w);
      ((ushort4*)xb)[i] = o;
    }
    if (i < nz4) {
      ((uint4*)zbase)[i] = make_uint4(0, 0, 0, 0);
    }
  }
}

// -------- bf16 MFMA GEMM, 128x128 tile, BK=64, 2-phase double-buffered LDS --------
// Blocks >= gemmBlocks run the (independent) CSR-lite slot-fill: both depend only
// on prep, so they share one dispatch (layer-1 launch only). Grid 8*MBLK*6 for the
// gemm part: XCD x = blockIdx&7 owns a contiguous m-strip; B (1.2 MB) L2-resident.
__global__ __launch_bounds__(256)
void gemm_kernel(const ushort_t* __restrict__ A, const ushort_t* __restrict__ Bt,
                 const float* __restrict__ att_s, const float* __restrict__ att_d,
                 float* __restrict__ a_s, float* __restrict__ a_d,
                 ushort_t* __restrict__ Hb, int M, int MBLK,
                 const int* __restrict__ ei, int* __restrict__ degw,
                 int* __restrict__ colw, int E, int Etot, int gemmBlocks) {
  const int K = DIM;
  __shared__ __align__(16) ushort_t As[2][128 * 64];   // 32 KB
  __shared__ __align__(16) ushort_t Bs[2][128 * 64];   // 32 KB
  int b = blockIdx.x;
  if (b >= gemmBlocks) {               // fused CSR path (layer-1 launch only)
    int e = (b - gemmBlocks) * 256 + threadIdx.x;
    if (e < Etot) {
      int s, d;
      if (e < E) { s = ei[e]; d = ei[E + e]; }
      else       { s = e - E; d = e - E; }
      int slot = atomicAdd(&degw[d], 1);
      if (slot < MAXDEG) colw[(size_t)d * MAXDEG + slot] = s;
    }
    return;
  }
  int x = b & 7, sidx = b >> 3;
  int m_local = sidx / 6, nblk = sidx - m_local * 6;
  int mblk = x * MBLK + m_local;
  if (mblk * 128 >= M) return;         // uniform per block: safe early-out
  int m0 = mblk * 128, n0 = nblk * 128;
  int tid = threadIdx.x;
  int wave = tid >> 6, lane = tid & 63;
  int quad = lane >> 4, l16 = lane & 15;
  int wr = wave >> 1, wc = wave & 1;   // 2x2 wave grid, 64x64 each

  floatx4 acc[4][4];
  const floatx4 fzero = {0.f, 0.f, 0.f, 0.f};
#pragma unroll
  for (int i = 0; i < 4; ++i)
#pragma unroll
    for (int j = 0; j < 4; ++j) acc[i][j] = fzero;

  int lr = lane >> 3, lc = lane & 7;
  const ushort_t* gA[4];
  const ushort_t* gB[4];
  ushort_t* lA[4];
  ushort_t* lB[4];
#pragma unroll
  for (int t = 0; t < 4; ++t) {
    int r = t * 32 + wave * 8 + lr;                 // 0..127
    int g = lc ^ (r & 7);
    gA[t] = A + (size_t)min(m0 + r, M - 1) * K + g * 8;
    gB[t] = Bt + (size_t)(n0 + r) * K + g * 8;
    lA[t] = &As[0][(t * 32 + wave * 8) * 64];
    lB[t] = &Bs[0][(t * 32 + wave * 8) * 64];
  }

#define GEMM_STAGE(k0_, buf_)                                         \
  {                                                                   \
    _Pragma("unroll")                                                 \
    for (int t = 0; t < 4; ++t) gl2lds16(gA[t] + (k0_), lA[t] + (buf_)*8192); \
    _Pragma("unroll")                                                 \
    for (int t = 0; t < 4; ++t) gl2lds16(gB[t] + (k0_), lB[t] + (buf_)*8192); \
  }

  GEMM_STAGE(0, 0);
  __syncthreads();                     // drains vmcnt(0): buf0 ready
  int cur = 0;

  for (int k0 = 0; k0 < K; k0 += 64) {
    if (k0 + 64 < K) GEMM_STAGE(k0 + 64, cur ^ 1);   // prefetch next tile
    const ushort_t* Ab = &As[cur][0];
    const ushort_t* Bb = &Bs[cur][0];
#pragma unroll
    for (int h = 0; h < 2; ++h) {
      short8 af[4], bfr[4];
#pragma unroll
      for (int i = 0; i < 4; ++i) {
        int ra = wr * 64 + i * 16 + l16;
        af[i] = *(const short8*)(Ab + ra * 64 + ((((h << 2) | quad)) ^ (ra & 7)) * 8);
      }
#pragma unroll
      for (int j = 0; j < 4; ++j) {
        int rb = wc * 64 + j * 16 + l16;
        bfr[j] = *(const short8*)(Bb + rb * 64 + ((((h << 2) | quad)) ^ (rb & 7)) * 8);
      }
#pragma unroll
      for (int i = 0; i < 4; ++i)
#pragma unroll
        for (int j = 0; j < 4; ++j)
          acc[i][j] = __builtin_amdgcn_mfma_f32_16x16x32_bf16(af[i], bfr[j], acc[i][j], 0, 0, 0);
    }
    __syncthreads();                   // drains prefetch; next buf ready
    cur ^= 1;
  }

  float avs[4], avd[4];
#pragma unroll
  for (int j = 0; j < 4; ++j) {
    int c = n0 + wc * 64 + j * 16 + l16;
    avs[j] = att_s[c];
    avd[j] = att_d[c];
  }

#pragma unroll
  for (int i = 0; i < 4; ++i) {
#pragma unroll
    for (int r2 = 0; r2 < 4; ++r2) {
      int row = m0 + wr * 64 + i * 16 + quad * 4 + r2;
      bool valid = row < M;
      float pvs = 0.f, pvd = 0.f;
#pragma unroll
      for (int j = 0; j < 4; ++j) {
        float v = acc[i][j][r2];
        if (valid) Hb[(size_t)row * DIM + n0 + wc * 64 + j * 16 + l16] = f32_to_bf16(v);
        pvs = fmaf(v, avs[j], pvs);
        pvd = fmaf(v, avd[j], pvd);
      }
#pragma unroll
      for (int off = 1; off < 16; off <<= 1) {
        pvs += __shfl_xor(pvs, off, 64);
        pvd += __shfl_xor(pvd, off, 64);
      }
      if (valid && l16 == 0) {
        atomicAdd(a_s + row, pvs);
        atomicAdd(a_d + row, pvd);
      }
    }
  }
}

// ---------------- wave-per-node segment softmax + gather-sum (bf16 h) ----------------
// Depth-3 chunk pipeline (A/B/C: 12 rows in flight) with chunks 0 AND 1 issued
// BEFORE the softmax latency chain (they depend only on col). For dg<=8 all rows
// are in flight before the first FMA. FMA chunk order stays ascending -> bitwise
// identical accumulation vs depth-2. Dead lanes duplicate a valid src (w=0).
__global__ __launch_bounds__(256)
void aggregate_kernel(const ushort_t* __restrict__ h, const float* __restrict__ a_s,
                      const float* __restrict__ a_d, const int* __restrict__ deg,
                      const int* __restrict__ col, const float* __restrict__ bias,
                      float* __restrict__ out_f32, ushort_t* __restrict__ out_bf16,
                      int relu_mode, int N) {
  int wave = threadIdx.x >> 6, lane = threadIdx.x & 63;
  int node = blockIdx.x * 4 + wave;
  if (node >= N) return;
  int dg = min(deg[node], MAXDEG);     // >=1 always (self-loop)
  int base = node * MAXDEG;
  float ad = a_d[node];

  bool has = lane < dg;
  int sc = col[base + min(lane, dg - 1)];   // dead lanes dup last valid edge
  int dgc = (dg + 3) & ~3;             // chunk-of-4 round-up (w=0 dup-row tail)

  uint4 uA[4], uB[4], uC[4];
  ushort4 tA[4], tB[4], tC[4];
  float wA[4], wB[4], wC[4];

#define GAT_LOADR(b_, u_, t_)                                         \
  {                                                                   \
    _Pragma("unroll")                                                 \
    for (int q = 0; q < 4; ++q) {                                     \
      int s_ = __shfl(sc, (b_) + q, 64);                              \
      const ushort_t* hr_ = h + (size_t)s_ * DIM;                     \
      u_[q] = *(const uint4*)(hr_ + lane * 8);                        \
      t_[q] = *(const ushort4*)(hr_ + 512 + lane * 4);                \
    }                                                                 \
  }

#define GAT_LOADW(b_, w_)                                             \
  {                                                                   \
    _Pragma("unroll")                                                 \
    for (int q = 0; q < 4; ++q) w_[q] = __shfl(al, (b_) + q, 64);     \
  }

#define GAT_FMAC(u_, t_, w_)                                          \
  {                                                                   \
    _Pragma("unroll")                                                 \
    for (int q = 0; q < 4; ++q) {                                     \
      float w = w_[q];                                                \
      acc8[0] = fmaf(w, bf16lo(u_[q].x), acc8[0]);                    \
      acc8[1] = fmaf(w, bf16hi(u_[q].x), acc8[1]);                    \
      acc8[2] = fmaf(w, bf16lo(u_[q].y), acc8[2]);                    \
      acc8[3] = fmaf(w, bf16hi(u_[q].y), acc8[3]);                    \
      acc8[4] = fmaf(w, bf16lo(u_[q].z), acc8[4]);                    \
      acc8[5] = fmaf(w, bf16hi(u_[q].z), acc8[5]);                    \
      acc8[6] = fmaf(w, bf16lo(u_[q].w), acc8[6]);                    \
      acc8[7] = fmaf(w, bf16hi(u_[q].w), acc8[7]);                    \
      acc4[0] = fmaf(w, bf16_to_f32(t_[q].x), acc4[0]);               \
      acc4[1] = fmaf(w, bf16_to_f32(t_[q].y), acc4[1]);               \
      acc4[2] = fmaf(w, bf16_to_f32(t_[q].z), acc4[2]);               \
      acc4[3] = fmaf(w, bf16_to_f32(t_[q].w), acc4[3]);               \
    }                                                                 \
  }

  // chunks 0 and 1 in flight while the softmax chain (random a_s gather + 12
  // shuffles + exp) runs
  GAT_LOADR(0, uA, tA);
  if (4 < dgc) GAT_LOADR(4, uB, tB);

  float v = a_s[sc] + ad;
  v = (v > 0.f) ? v : NEG_SLOPE * v;
  float vmax = v;
#pragma unroll
  for (int off = 32; off > 0; off >>= 1) vmax = fmaxf(vmax, __shfl_xor(vmax, off, 64));
  float ex = has ? __expf(v - vmax) : 0.f;
  float ssum = ex;
#pragma unroll
  for (int off = 32; off > 0; off >>= 1) ssum += __shfl_xor(ssum, off, 64);
  float al = ex * (1.f / ssum);        // per-lane alpha; 0 for dead lanes

  float acc8[8];
  float acc4[4];
#pragma unroll
  for (int k = 0; k < 8; ++k) acc8[k] = 0.f;
#pragma unroll
  for (int k = 0; k < 4; ++k) acc4[k] = 0.f;

  GAT_LOADW(0, wA);
  if (4 < dgc) GAT_LOADW(4, wB);
  if (8 < dgc) { GAT_LOADR(8, uC, tC); GAT_LOADW(8, wC); }

  for (int bb = 0; bb < dgc; bb += 12) {
    GAT_FMAC(uA, tA, wA);
    if (bb + 12 < dgc) { GAT_LOADR(bb + 12, uA, tA); GAT_LOADW(bb + 12, wA); }
    if (bb + 4 < dgc) {
      GAT_FMAC(uB, tB, wB);
      if (bb + 16 < dgc) { GAT_LOADR(bb + 16, uB, tB); GAT_LOADW(bb + 16, wB); }
    }
    if (bb + 8 < dgc) {
      GAT_FMAC(uC, tC, wC);
      if (bb + 20 < dgc) { GAT_LOADR(bb + 20, uC, tC); GAT_LOADW(bb + 20, wC); }
    }
  }
#undef GAT_LOADR
#undef GAT_LOADW
#undef GAT_FMAC

  size_t ob = (size_t)node * DIM;
  int c8 = lane * 8, c4 = 512 + lane * 4;
  float4 b0 = *(const float4*)(bias + c8);
  float4 b1 = *(const float4*)(bias + c8 + 4);
  float4 b2 = *(const float4*)(bias + c4);
  float o[12];
  o[0] = acc8[0] + b0.x; o[1] = acc8[1] + b0.y;
  o[2] = acc8[2] + b0.z; o[3] = acc8[3] + b0.w;
  o[4] = acc8[4] + b1.x; o[5] = acc8[5] + b1.y;
  o[6] = acc8[6] + b1.z; o[7] = acc8[7] + b1.w;
  o[8] = acc4[0] + b2.x; o[9] = acc4[1] + b2.y;
  o[10] = acc4[2] + b2.z; o[11] = acc4[3] + b2.w;
  if (relu_mode) {
#pragma unroll
    for (int k = 0; k < 12; ++k) o[k] = fmaxf(o[k], 0.f);
    uint4 s0;
    s0.x = pack_bf16x2(o[0], o[1]);
    s0.y = pack_bf16x2(o[2], o[3]);
    s0.z = pack_bf16x2(o[4], o[5]);
    s0.w = pack_bf16x2(o[6], o[7]);
    *(uint4*)(out_bf16 + ob + c8) = s0;
    uint2 s1;
    s1.x = pack_bf16x2(o[8], o[9]);
    s1.y = pack_bf16x2(o[10], o[11]);
    *(uint2*)(out_bf16 + ob + c4) = s1;
  } else {
    *(float4*)(out_f32 + ob + c8) = make_float4(o[0], o[1], o[2], o[3]);
    *(float4*)(out_f32 + ob + c8 + 4) = make_float4(o[4], o[5], o[6], o[7]);
    *(float4*)(out_f32 + ob + c4) = make_float4(o[8], o[9], o[10], o[11]);
  }
}

extern "C" void kernel_launch(void* const* d_in, const int* in_sizes, int n_in,
                              void* d_out, int out_size, void* d_ws, size_t ws_size,
                              hipStream_t stream) {
  const float* x   = (const float*)d_in[0];
  const int*   ei  = (const int*)d_in[1];
  const float* W1  = (const float*)d_in[2];
  const float* as1 = (const float*)d_in[3];
  const float* ad1 = (const float*)d_in[4];
  const float* b1  = (const float*)d_in[5];
  const float* W2  = (const float*)d_in[6];
  const float* as2 = (const float*)d_in[7];
  const float* ad2 = (const float*)d_in[8];
  const float* b2  = (const float*)d_in[9];

  const int N = in_sizes[0] / DIM;   // 10000
  const int E = in_sizes[1] / 2;     // 100000
  const int Etot = E + N;

  char* p = (char*)d_ws;
  auto alloc = [&](size_t bytes) {
    char* q = p;
    p += (bytes + 255) & ~(size_t)255;
    return q;
  };
  ushort_t* Hb     = (ushort_t*)alloc((size_t)N * DIM * 2);
  ushort_t* xb     = (ushort_t*)alloc((size_t)N * DIM * 2);
  ushort_t* wT1    = (ushort_t*)alloc((size_t)DIM * DIM * 2);
  ushort_t* wT2    = (ushort_t*)alloc((size_t)DIM * DIM * 2);
  // contiguous zeroed region: deg | a_s1 | a_d1 | a_s2 | a_d2  (zeroed in prep)
  int*      zbase  = (int*)alloc((size_t)5 * N * 4 + 16);
  int*      deg    = zbase;
  float*    a_s1   = (float*)(zbase + N);
  float*    a_d1   = (float*)(zbase + 2 * N);
  float*    a_s2   = (float*)(zbase + 3 * N);
  float*    a_d2   = (float*)(zbase + 4 * N);
  int*      col    = (int*)alloc((size_t)N * MAXDEG * 4);

  int n4 = N * DIM / 4;
  int nz4 = (5 * N + 3) / 4;
  int prep_blocks = 288 + (n4 + 255) / 256;
  prep_kernel<<<prep_blocks, 256, 0, stream>>>(x, xb, n4, W1, wT1, W2, wT2,
                                               zbase, nz4);

  int MB = (N + 127) / 128;          // 79 m-blocks
  int MBLK = (MB + 7) / 8;           // 10 m-blocks per XCD strip
  int gemm_blocks = 8 * MBLK * 6;    // 480
  int csr_blocks = (Etot + 255) / 256;           // 430
  int agg_blocks = (N + 3) / 4;      // 2500

  // Layer 1 (gemm + fused CSR slot-fill: both depend only on prep)
  gemm_kernel<<<gemm_blocks + csr_blocks, 256, 0, stream>>>(
      xb, wT1, as1, ad1, a_s1, a_d1, Hb, N, MBLK, ei, deg, col, E, Etot, gemm_blocks);
  aggregate_kernel<<<agg_blocks, 256, 0, stream>>>(Hb, a_s1, a_d1, deg, col, b1,
                                                   nullptr, xb, 1, N);
  // Layer 2
  gemm_kernel<<<gemm_blocks, 256, 0, stream>>>(
      xb, wT2, as2, ad2, a_s2, a_d2, Hb, N, MBLK, ei, deg, col, E, 0, gemm_blocks);
  aggregate_kernel<<<agg_blocks, 256, 0, stream>>>(Hb, a_s2, a_d2, deg, col, b2,
                                                   (float*)d_out, nullptr, 0, N);
}